// Round 14
// baseline (84.853 us; speedup 1.0000x reference)
//
#include <hip/hip_runtime.h>
#include <math.h>

// HoltWintersDecomposition: x (8192, 2048) f32, sequential per-row recurrence.
// r14 = r13 + TWO consumer waves (the consumer is now the critical path):
//   r13 evidence: chain shortened by ~30 cy/step gave only -5us -> producer no
//   longer binding. Consumer per tile = 24KB stores + vmcnt(0) drain, all
//   serial on one wave (~6200 cy/tile vs ~2600 fair-share). Splitting stores
//   across two consumer waves overlaps their issue + drain latencies.
//   - block = 192: wave0 producer (32 rows, register x prefetch, shortened
//     rcp->fma->rcp->fma chain), waves 1-2 consumers (half-tile stores each).
//   - 256 blocks -> one trio per CU; 1 barrier per tile (all waves).
// Lessons kept: r12 never shrink producer active lanes; r9 producer global
// loads need >= 1-tile distance; r6 parallel-in-time is mathematically broken
// here (s ~ 20*EPS; EPS breaks the scale invariance).

constexpr int   T    = 2048;
constexpr int   B    = 8192;
constexpr int   RPB  = 32;        // rows per block
constexpr int   TT   = 64;        // steps per tile
constexpr int   NTI  = T / TT;    // 32 tiles
constexpr int   LSX  = 68;        // LDS stride words: 272B rows, 16B-aligned
constexpr float EPS  = 1e-8f;

__global__ __launch_bounds__(192, 1)
void hw_kernel(const float* __restrict__ x,
               const float* __restrict__ pla,
               const float* __restrict__ plg,
               float* __restrict__ out)
{
    __shared__ alignas(16) float LT[2][RPB][LSX];
    __shared__ alignas(16) float ST[2][RPB][LSX];
    __shared__ alignas(16) float YT[2][RPB][LSX];

    const int tid  = threadIdx.x;
    const int wid  = tid >> 6;        // 0 = producer, 1..2 = consumers
    const int lane = tid & 63;
    const int row0 = blockIdx.x * RPB;

    const float alpha = 1.0f / (1.0f + expf(-pla[0]));
    const float gamma = 1.0f / (1.0f + expf(-plg[0]));
    const float oma = 1.0f - alpha, omg = 1.0f - gamma;
    const float EPSa = EPS * alpha;   // folds +EPS into the l fma constant
    const float EPSg = EPS * gamma;   // folds +EPS into the s fma constant

    float* __restrict__ lout = out;
    float* __restrict__ sout = out + (size_t)B * T;
    float* __restrict__ yout = out + (size_t)2 * B * T;

    // store-phase lane mapping
    const int cr = lane >> 4;          // 0..3
    const int cc = (lane & 15) << 2;   // 0,4,...,60

    auto store_tile = [&](int m, int itlo, int ithi) {
        const int bsel = m & 1;
        const int t0 = m * TT;
        for (int it = itlo; it < ithi; ++it) {
            const int r = 4 * it + cr;
            const size_t g = (size_t)(row0 + r) * T + t0 + cc;
            const float4 vl = *reinterpret_cast<const float4*>(&LT[bsel][r][cc]);
            const float4 vs = *reinterpret_cast<const float4*>(&ST[bsel][r][cc]);
            const float4 vy = *reinterpret_cast<const float4*>(&YT[bsel][r][cc]);
            *reinterpret_cast<float4*>(&lout[g]) = vl;
            *reinterpret_cast<float4*>(&sout[g]) = vs;
            *reinterpret_cast<float4*>(&yout[g]) = vy;
        }
    };

    if (wid == 0) {
        // ================= producer =================
        const bool act = lane < RPB;
        const float* __restrict__ xrow = x + (size_t)(row0 + (act ? lane : 0)) * T;

        float lpe = 0.0f, spe = 1.0f;   // primed state: l+EPS, s+EPS
        float4 XA[16], XB[16];

        auto loadX = [&](float4* Xb, int k) {
            const float* p = xrow + k * TT;
            #pragma unroll
            for (int i = 0; i < 16; ++i)
                Xb[i] = *reinterpret_cast<const float4*>(p + 4 * i);
        };

        // chain: rcp -> fma -> rcp -> fma; everything else off-chain
        auto do_step = [&](float xt, float& lo, float& so, float& yo) {
            const float axt = alpha * xt;                         // off-chain
            const float gxt = gamma * xt;                         // off-chain
            const float cl  = __builtin_fmaf(oma, lpe, EPSa);     // off-chain
            const float rs  = __builtin_amdgcn_rcpf(spe);         // chain
            const float lte = __builtin_fmaf(axt, rs, cl);        // chain (= l_t+EPS)
            const float cs  = __builtin_fmaf(omg, spe, EPSg);     // off-chain
            const float rl  = __builtin_amdgcn_rcpf(lte);         // chain
            const float ste = __builtin_fmaf(gxt, rl, cs);        // chain (= s_t+EPS)
            const float lt  = lte - EPS;                          // off-chain
            const float st  = ste - EPS;                          // off-chain
            yo = xt * __builtin_amdgcn_rcpf(__builtin_fmaf(lt, st, EPS));
            lo = lt; so = st;
            lpe = lte; spe = ste;
        };

        auto compute_tile = [&](const float4* Xb, int k, bool first) {
            const int bsel = k & 1;
            #pragma unroll
            for (int g = 0; g < 16; ++g) {
                const float4 xv = Xb[g];
                float4 lv, sv, yv;
                if (first && g == 0) {
                    // t == 0: l0 = x0, s0 = 1, y0 = x0/(x0*1 + eps)
                    lv.x = xv.x; sv.x = 1.0f;
                    yv.x = xv.x * __builtin_amdgcn_rcpf(__builtin_fmaf(xv.x, 1.0f, EPS));
                    lpe = xv.x + EPS; spe = 1.0f + EPS;
                    do_step(xv.y, lv.y, sv.y, yv.y);
                    do_step(xv.z, lv.z, sv.z, yv.z);
                    do_step(xv.w, lv.w, sv.w, yv.w);
                } else {
                    do_step(xv.x, lv.x, sv.x, yv.x);
                    do_step(xv.y, lv.y, sv.y, yv.y);
                    do_step(xv.z, lv.z, sv.z, yv.z);
                    do_step(xv.w, lv.w, sv.w, yv.w);
                }
                *reinterpret_cast<float4*>(&LT[bsel][lane][4 * g]) = lv;
                *reinterpret_cast<float4*>(&ST[bsel][lane][4 * g]) = sv;
                *reinterpret_cast<float4*>(&YT[bsel][lane][4 * g]) = yv;
            }
        };

        if (act) { loadX(XA, 0); loadX(XB, 1); }
        if (act) compute_tile(XA, 0, true);     // one-time vmcnt wait on XA
        __syncthreads();

        #pragma unroll 1
        for (int k = 1; k < NTI - 1; k += 2) {
            if (act) { loadX(XA, k + 1); compute_tile(XB, k, false); }
            __syncthreads();
            if (act) { loadX(XB, k + 2); compute_tile(XA, k + 1, false); }
            __syncthreads();
        }
        if (act) compute_tile(XB, NTI - 1, false);
        __syncthreads();
    } else {
        // ================= consumers: stores only, half tile each =========
        const int lo = (wid - 1) * 4;            // wave1: 0..3, wave2: 4..7
        #pragma unroll 1
        for (int k = 0; k < NTI; ++k) {
            if (k > 0) store_tile(k - 1, lo, lo + 4);
            __syncthreads();
        }
    }

    // epilogue: tile 31 (buffer 1), all three waves split the 8 store groups
    {
        const int lo = (wid == 0) ? 0 : (wid == 1) ? 2 : 5;
        const int hi = (wid == 0) ? 2 : (wid == 1) ? 5 : 8;
        store_tile(NTI - 1, lo, hi);
    }
}

extern "C" void kernel_launch(void* const* d_in, const int* in_sizes, int n_in,
                              void* d_out, int out_size, void* d_ws, size_t ws_size,
                              hipStream_t stream) {
    const float* x   = (const float*)d_in[0];
    const float* pla = (const float*)d_in[1];
    const float* plg = (const float*)d_in[2];
    float* out = (float*)d_out;

    dim3 grid(B / RPB);    // 256 blocks -> one producer + 2 consumers per CU
    dim3 block(192);       // wave0 producer, waves 1-2 consumers
    hw_kernel<<<grid, block, 0, stream>>>(x, pla, plg, out);
}

// Round 15
// 70.346 us; speedup vs baseline: 1.2062x; 1.2062x over previous
//
#include <hip/hip_runtime.h>
#include <math.h>

// HoltWintersDecomposition: x (8192, 2048) f32, sequential per-row recurrence.
// r15 = r13 structure + deferred-y + primed-store (issue-work diet):
//   - deferred y (validated in r12, absmax 16384): y_t = xrl_t * rs_{t+1}
//     reuses the chain's two rcps -> removes the 3rd rcp (+fma+mul) per step.
//     Tile epilogue finalizes y[63] with rcp(spe) (bitwise-equal to the next
//     step's rs). First step of each tile does NOT finalize (already flushed).
//   - primed-store: output l/s as lpe/spe (= l+1e-8, s+1e-8; negligible) ->
//     removes 2 subs/step.
//   Per-step: 2 rcp + 7 VALU ~ 30 issue-cy (r13: ~44). Chain unchanged:
//   rcp -> fma -> rcp -> fma. This round discriminates issue-bound (expect
//   ~67us) vs rcp-latency-bound (expect ~82us, => ~75us floor).
// Structure (r13, 82.6us): 256 blocks x 32 rows; wave0 producer (32 lanes,
// full-tile x register prefetch, 1-tile distance covers barrier vmcnt drain),
// wave1 consumer (transposed full-line stores); 1 barrier/tile.
// Lessons: r12 never shrink producer active lanes; r9 producer global loads
// need >= 1-tile distance; r6 parallel-in-time mathematically broken (s~20*EPS).

constexpr int   T    = 2048;
constexpr int   B    = 8192;
constexpr int   RPB  = 32;        // rows per block
constexpr int   TT   = 64;        // steps per tile
constexpr int   NTI  = T / TT;    // 32 tiles
constexpr int   LSX  = 68;        // LDS stride words: 272B rows, 16B-aligned
constexpr float EPS  = 1e-8f;

__global__ __launch_bounds__(128, 1)
void hw_kernel(const float* __restrict__ x,
               const float* __restrict__ pla,
               const float* __restrict__ plg,
               float* __restrict__ out)
{
    __shared__ alignas(16) float LT[2][RPB][LSX];
    __shared__ alignas(16) float ST[2][RPB][LSX];
    __shared__ alignas(16) float YT[2][RPB][LSX];

    const int tid  = threadIdx.x;
    const int wid  = tid >> 6;        // 0 = producer, 1 = consumer
    const int lane = tid & 63;
    const int row0 = blockIdx.x * RPB;

    const float alpha = 1.0f / (1.0f + expf(-pla[0]));
    const float gamma = 1.0f / (1.0f + expf(-plg[0]));
    const float oma = 1.0f - alpha, omg = 1.0f - gamma;
    const float EPSa = EPS * alpha;   // folds +EPS into the l fma constant
    const float EPSg = EPS * gamma;   // folds +EPS into the s fma constant

    float* __restrict__ lout = out;
    float* __restrict__ sout = out + (size_t)B * T;
    float* __restrict__ yout = out + (size_t)2 * B * T;

    // store-phase lane mapping (both waves use it in the epilogue)
    const int cr = lane >> 4;          // 0..3
    const int cc = (lane & 15) << 2;   // 0,4,...,60

    auto store_tile = [&](int m, int itlo, int ithi) {
        const int bsel = m & 1;
        const int t0 = m * TT;
        for (int it = itlo; it < ithi; ++it) {
            const int r = 4 * it + cr;
            const size_t g = (size_t)(row0 + r) * T + t0 + cc;
            const float4 vl = *reinterpret_cast<const float4*>(&LT[bsel][r][cc]);
            const float4 vs = *reinterpret_cast<const float4*>(&ST[bsel][r][cc]);
            const float4 vy = *reinterpret_cast<const float4*>(&YT[bsel][r][cc]);
            *reinterpret_cast<float4*>(&lout[g]) = vl;
            *reinterpret_cast<float4*>(&sout[g]) = vs;
            *reinterpret_cast<float4*>(&yout[g]) = vy;
        }
    };

    if (wid == 0) {
        // ================= producer =================
        const bool act = lane < RPB;
        const float* __restrict__ xrow = x + (size_t)(row0 + (act ? lane : 0)) * T;

        float lpe = 0.0f, spe = 1.0f;   // primed state: l+EPS, s+EPS
        float xrl = 0.0f;               // x_t * rcp(l_t+EPS), carried for y
        float4 XA[16], XB[16];

        auto loadX = [&](float4* Xb, int k) {
            const float* p = xrow + k * TT;
            #pragma unroll
            for (int i = 0; i < 16; ++i)
                Xb[i] = *reinterpret_cast<const float4*>(p + 4 * i);
        };

        // chain: rcp -> fma -> rcp -> fma; y finalization + constants off-chain
        auto do_step = [&](float xt, float& lo, float& so, bool fin, float& yprev) {
            const float rs  = __builtin_amdgcn_rcpf(spe);         // chain
            if (fin) yprev  = xrl * rs;                           // finalize y[t-1]
            const float cl  = __builtin_fmaf(oma, lpe, EPSa);     // off-chain
            const float lte = __builtin_fmaf(alpha * xt, rs, cl); // chain (= l_t+EPS)
            const float cs  = __builtin_fmaf(omg, spe, EPSg);     // off-chain
            const float rl  = __builtin_amdgcn_rcpf(lte);         // chain
            const float ste = __builtin_fmaf(gamma * xt, rl, cs); // chain (= s_t+EPS)
            xrl = xt * rl;                                        // off-chain branch
            lo = lte; so = ste;                                   // primed store
            lpe = lte; spe = ste;
        };

        auto compute_tile = [&](const float4* Xb, int k, bool first) {
            const int bsel = k & 1;
            float4 yv;
            #pragma unroll
            for (int g = 0; g < 16; ++g) {
                const float4 xv = Xb[g];
                float4 lv, sv;
                if (first && g == 0) {
                    // t == 0: l0 = x0 (exact), s0 = 1; y0 deferred via xrl
                    lv.x = xv.x; sv.x = 1.0f;
                    lpe = xv.x + EPS; spe = 1.0f + EPS;
                    xrl = xv.x * __builtin_amdgcn_rcpf(lpe);
                } else {
                    do_step(xv.x, lv.x, sv.x, g > 0, yv.w);
                }
                if (g > 0)
                    *reinterpret_cast<float4*>(&YT[bsel][lane][4 * (g - 1)]) = yv;
                do_step(xv.y, lv.y, sv.y, true, yv.x);
                do_step(xv.z, lv.z, sv.z, true, yv.y);
                do_step(xv.w, lv.w, sv.w, true, yv.z);
                *reinterpret_cast<float4*>(&LT[bsel][lane][4 * g]) = lv;
                *reinterpret_cast<float4*>(&ST[bsel][lane][4 * g]) = sv;
            }
            // finalize y[63]: rs of the next step, computed off-chain here
            yv.w = xrl * __builtin_amdgcn_rcpf(spe);
            *reinterpret_cast<float4*>(&YT[bsel][lane][60]) = yv;
        };

        if (act) { loadX(XA, 0); loadX(XB, 1); }
        if (act) compute_tile(XA, 0, true);     // one-time vmcnt wait on XA
        __syncthreads();

        #pragma unroll 1
        for (int k = 1; k < NTI - 1; k += 2) {
            if (act) { loadX(XA, k + 1); compute_tile(XB, k, false); }
            __syncthreads();
            if (act) { loadX(XB, k + 2); compute_tile(XA, k + 1, false); }
            __syncthreads();
        }
        if (act) compute_tile(XB, NTI - 1, false);
        __syncthreads();
    } else {
        // ================= consumer: stores only =================
        #pragma unroll 1
        for (int k = 0; k < NTI; ++k) {
            if (k > 0) store_tile(k - 1, 0, 8);
            __syncthreads();
        }
    }

    // epilogue: tile 31 (buffer 1), both waves split the 8 store groups
    store_tile(NTI - 1, wid * 4, wid * 4 + 4);
}

extern "C" void kernel_launch(void* const* d_in, const int* in_sizes, int n_in,
                              void* d_out, int out_size, void* d_ws, size_t ws_size,
                              hipStream_t stream) {
    const float* x   = (const float*)d_in[0];
    const float* pla = (const float*)d_in[1];
    const float* plg = (const float*)d_in[2];
    float* out = (float*)d_out;

    dim3 grid(B / RPB);    // 256 blocks -> one producer/consumer pair per CU
    dim3 block(128);       // wave 0 = producer (32 rows), wave 1 = consumer
    hw_kernel<<<grid, block, 0, stream>>>(x, pla, plg, out);
}